// Round 10
// baseline (76.497 us; speedup 1.0000x reference)
//
#include <hip/hip_runtime.h>
#include <math.h>

#define D_ 10
#define N_ 500
#define REC_H 184   // per-(d,n) record, f16 half-units (368 B)

typedef float f32x2 __attribute__((ext_vector_type(2)));
typedef _Float16 h2 __attribute__((ext_vector_type(2)));

__device__ __forceinline__ float fexp2(float x){ return __builtin_amdgcn_exp2f(x); }
__device__ __forceinline__ float flog2(float x){ return __builtin_amdgcn_logf(x); }
__device__ __forceinline__ float frcp (float x){ return __builtin_amdgcn_rcpf(x); }

// cvt_pkrtz returns an __fp16 vector; bit-cast to our h2.
__device__ __forceinline__ h2 cvt_pk(float a, float b){
  return __builtin_bit_cast(h2, __builtin_amdgcn_cvt_pkrtz(a, b));
}

#define LOG2E 1.4426950408889634f
#define LN2   0.6931471805599453f

__device__ __forceinline__ float fast_tanh(float x){
  float e = fexp2(x * (2.0f*LOG2E));
  return 1.0f - 2.0f*frcp(e + 1.0f);
}
__device__ __forceinline__ float softplus10(float x){
  float e = fexp2(x * (10.0f*LOG2E));
  return (0.1f*LN2) * flog2(1.0f + e);
}

// ---- packed f16 prims (VOP3P, full-rate). Weight = wave-uniform SGPR word
// holding 2 f16; op_sel/op_sel_hi broadcast the chosen half to both lanes'
// halves. Max 1 SGPR source per instr (the weight) -- legal.
__device__ __forceinline__ h2 pkh_fma_blo(h2 a, unsigned w, h2 c){
  h2 d; asm("v_pk_fma_f16 %0, %1, %2, %3 op_sel:[0,0,0] op_sel_hi:[1,0,1]"
            : "=v"(d) : "v"(a), "s"(w), "v"(c)); return d; }
__device__ __forceinline__ h2 pkh_fma_bhi(h2 a, unsigned w, h2 c){
  h2 d; asm("v_pk_fma_f16 %0, %1, %2, %3 op_sel:[0,1,0] op_sel_hi:[1,1,1]"
            : "=v"(d) : "v"(a), "s"(w), "v"(c)); return d; }
__device__ __forceinline__ h2 pkh_mul_blo(h2 a, unsigned w){
  h2 d; asm("v_pk_mul_f16 %0, %1, %2 op_sel:[0,0] op_sel_hi:[1,0]"
            : "=v"(d) : "v"(a), "s"(w)); return d; }
__device__ __forceinline__ h2 pkh_mul_bhi(h2 a, unsigned w){
  h2 d; asm("v_pk_mul_f16 %0, %1, %2 op_sel:[0,1] op_sel_hi:[1,1]"
            : "=v"(d) : "v"(a), "s"(w)); return d; }
__device__ __forceinline__ h2 pkh_mul(h2 a, h2 b){
  h2 d; asm("v_pk_mul_f16 %0, %1, %2" : "=v"(d) : "v"(a), "v"(b)); return d; }
__device__ __forceinline__ h2 pkh_nfma(h2 a, h2 b, h2 c){ // c - a*b
  h2 d; asm("v_pk_fma_f16 %0, %1, %2, %3 neg_lo:[1,0,0] neg_hi:[1,0,0]"
            : "=v"(d) : "v"(a), "v"(b), "v"(c)); return d; }

// hh = half-index into record; parity selects broadcast half.
#define LDW(hh)          (*(const unsigned*)(rw16 + ((hh) & ~1)))
#define FMH_B(a, hh, c)  (((hh)&1) ? pkh_fma_bhi((a), LDW(hh), (c)) : pkh_fma_blo((a), LDW(hh), (c)))
#define MUH_B(a, hh)     (((hh)&1) ? pkh_mul_bhi((a), LDW(hh))      : pkh_mul_blo((a), LDW(hh)))

// f32 activation on f16 pre: cvt up, exp-based tanh with paired rcp, cvt down.
__device__ __forceinline__ void act_tanh(h2 pre, h2 ONEH, h2* th, h2* td){
  float p0 = (float)pre.x, p1 = (float)pre.y;
  float e0 = fexp2(p0 * (2.0f*LOG2E));
  float e1 = fexp2(p1 * (2.0f*LOG2E));
  float q0 = e0 + 1.0f, q1 = e1 + 1.0f;
  float rr = frcp(q0 * q1);
  float t0 = 1.0f - 2.0f*(q1*rr);
  float t1 = 1.0f - 2.0f*(q0*rr);
  h2 t = cvt_pk(t0, t1);
  *th = t;
  *td = pkh_nfma(t, t, ONEH);   // 1 - th^2
}

// f16 record layout (half-units, 182 used pad 184):
//   [0..4] W0   [5..9] b0   [10..14] ta0
//   mid l=0..3 at B=15+40l: [B+j*5+k]=W^T (25), [B+25+j]=b, [B+30+j]=ta, pad 5
//   [175..179] Wl   [180] b_last   [181..183] pad
__global__ __launch_bounds__(256) void tennet_prep(
    const float* __restrict__ w_first, const float* __restrict__ w_mid,
    const float* __restrict__ w_last, const float* __restrict__ bs,
    const float* __restrict__ b_last, const float* __restrict__ a_all,
    unsigned short* __restrict__ rec16)
{
  int rid = blockIdx.x*4 + (threadIdx.x >> 6);
  int lane = threadIdx.x & 63;
  int d = rid / N_;
  int n = rid - d*N_;
  unsigned short* dst = rec16 + (unsigned)rid*REC_H;
  for (int i = lane; i < REC_H; i += 64) {
    float v = 0.0f;
    if (i < 5)        v = softplus10(w_first[(d*N_+n)*5 + i]);
    else if (i < 10)  v = bs[(d*N_+n)*5 + (i-5)];
    else if (i < 15)  v = fast_tanh(a_all[(d*N_+n)*5 + (i-10)]);
    else if (i < 175) {
      int q = i - 15; int l = q/40; int r2 = q - l*40;
      if (r2 < 25) {
        int j = r2/5, k = r2 - (r2/5)*5;
        v = softplus10(w_mid[((l*D_+d)*N_+n)*25 + k*5 + j]);
      } else if (r2 < 30) {
        v = bs[(((l+1)*D_+d)*N_+n)*5 + (r2-25)];
      } else if (r2 < 35) {
        v = fast_tanh(a_all[(((l+1)*D_+d)*N_+n)*5 + (r2-30)]);
      }
    }
    else if (i < 180) v = softplus10(w_last[(d*N_+n)*5 + (i-175)]);
    else if (i == 180) v = b_last[d*N_+n];
    _Float16 hv = (_Float16)v;
    dst[i] = __builtin_bit_cast(unsigned short, hv);
  }
}

// One wave per (d,n); 64 lanes x 2 m per thread (m, m+64) packed in f16 halves.
// Matvecs/state in full-rate v_pk_*_f16; activations in f32 (accuracy).
__global__ __launch_bounds__(512) void tennet_main(
    const float* __restrict__ X, const unsigned short* __restrict__ rec16,
    float* __restrict__ out0)
{
  __shared__ float tr[128*9];
  int bid = blockIdx.x;
  int mb  = bid & 7;            // 8 chunks of 128 m
  int q   = bid >> 3;
  int d   = q / 63;             // 10
  int nch = q - d*63;           // 63 chunks of 8 n (covers 504 >= 500)
  int n0 = nch*8;
  int t = threadIdx.x;
  int wv = __builtin_amdgcn_readfirstlane(t >> 6);   // uniform -> s_load weights
  int lane = t & 63;
  int n = n0 + wv;
  int nr = (n < N_) ? n : (N_-1);
  const unsigned short* rw16 = rec16 + (unsigned)(d*N_ + nr)*REC_H;
  int m0 = mb*128 + lane;

  float xa = X[m0*D_ + d];
  float xb = X[(m0+64)*D_ + d];
  h2 x = cvt_pk(xa, xb);

  h2 ONEH; ONEH.x = (_Float16)1.0f; ONEH.y = (_Float16)1.0f;

  h2 phis[5], phid[5];
  // layer 0 (k-dim = 1)
  #pragma unroll
  for (int j = 0; j < 5; ++j) {
    h2 bias = MUH_B(ONEH, 5+j);
    h2 pre = FMH_B(x, j, bias);
    h2 th, td;
    act_tanh(pre, ONEH, &th, &td);
    h2 uf = FMH_B(td, 10+j, ONEH);     // 1 + ta*td
    phid[j] = MUH_B(uf, j);            // W0 * uf
    phis[j] = FMH_B(th, 10+j, pre);    // pre + th*ta
  }
  // mid layers
  #pragma unroll
  for (int l = 0; l < 4; ++l) {
    const int B = 15 + l*40;
    h2 nphis[5], nphid[5];
    #pragma unroll
    for (int j = 0; j < 5; ++j) {
      h2 bias = MUH_B(ONEH, B + 25 + j);
      h2 pre = FMH_B(phis[0], B + j*5, bias);
      h2 pd  = MUH_B(phid[0], B + j*5);
      #pragma unroll
      for (int k = 1; k < 5; ++k) {
        pre = FMH_B(phis[k], B + j*5 + k, pre);
        pd  = FMH_B(phid[k], B + j*5 + k, pd);
      }
      h2 th, td;
      act_tanh(pre, ONEH, &th, &td);
      h2 uf = FMH_B(td, B + 30 + j, ONEH);
      nphid[j] = pkh_mul(pd, uf);
      nphis[j] = FMH_B(th, B + 30 + j, pre);
    }
    #pragma unroll
    for (int j = 0; j < 5; ++j){ phis[j]=nphis[j]; phid[j]=nphid[j]; }
  }
  // last layer + sigmoid' in f32
  h2 biasl = MUH_B(ONEH, 180);
  h2 preh = FMH_B(phis[0], 175, biasl);
  h2 pdh  = MUH_B(phid[0], 175);
  #pragma unroll
  for (int k = 1; k < 5; ++k) {
    preh = FMH_B(phis[k], 175 + k, preh);
    pdh  = FMH_B(phid[k], 175 + k, pdh);
  }
  float z0 = (float)preh.x, z1 = (float)preh.y;
  float e0 = fexp2(z0 * (-LOG2E));
  float e1 = fexp2(z1 * (-LOG2E));
  float q0 = e0 + 1.0f, q1 = e1 + 1.0f;
  float rr = frcp(q0 * q1);
  float s0 = q1*rr, s1 = q0*rr;
  float res0 = (float)pdh.x * s0 * (1.0f - s0);
  float res1 = (float)pdh.y * s1 * (1.0f - s1);

  // transpose 128m x 8n through LDS (stride 9 -> <=2-way banks, free)
  tr[lane*9 + wv]      = res0;
  tr[(lane+64)*9 + wv] = res1;
  __syncthreads();
  int tn = t & 7;
  #pragma unroll
  for (int p = 0; p < 2; ++p) {
    int rr2 = (t >> 3) + p*64;
    if (n0 + tn < N_)
      out0[((mb*128 + rr2)*D_ + d)*N_ + n0 + tn] = tr[rr2*9 + tn];
  }
}

// fm[m] = min_n mean_d( -ln(phidot[m,d,n] + 1e-10) )
__global__ __launch_bounds__(512) void tennet_fm(
    const float* __restrict__ out0, float* __restrict__ fm)
{
  int m = blockIdx.x;
  int t = threadIdx.x;
  float val = INFINITY;
  if (t < N_) {
    float acc = 0.0f;
    #pragma unroll
    for (int d = 0; d < D_; ++d) {
      float v = out0[(m*D_ + d)*N_ + t];
      acc += flog2(v + 1e-10f);
    }
    val = -acc * (LN2 / (float)D_);
  }
  #pragma unroll
  for (int off = 32; off; off >>= 1) {
    float o = __shfl_down(val, off, 64);
    val = fminf(val, o);
  }
  __shared__ float red[8];
  int wid = t >> 6;
  if ((t & 63) == 0) red[wid] = val;
  __syncthreads();
  if (t == 0) {
    float v = red[0];
    #pragma unroll
    for (int ww = 1; ww < 8; ++ww) v = fminf(v, red[ww]);
    fm[m] = v;
  }
}

extern "C" void kernel_launch(void* const* d_in, const int* in_sizes, int n_in,
                              void* d_out, int out_size, void* d_ws, size_t ws_size,
                              hipStream_t stream) {
  const float* X       = (const float*)d_in[0];
  const float* w_first = (const float*)d_in[1];
  const float* w_mid   = (const float*)d_in[2];
  const float* w_last  = (const float*)d_in[3];
  const float* bs      = (const float*)d_in[4];
  const float* b_last  = (const float*)d_in[5];
  const float* a_all   = (const float*)d_in[6];
  float* out0 = (float*)d_out;
  float* fm   = out0 + 1024*D_*N_;
  unsigned short* rec16 = (unsigned short*)d_ws;   // 5000*184*2 = 1.84 MB

  tennet_prep<<<(D_*N_)/4, 256, 0, stream>>>(w_first, w_mid, w_last, bs, b_last, a_all, rec16);
  tennet_main<<<10*63*8, 512, 0, stream>>>(X, rec16, out0);
  tennet_fm<<<1024, 512, 0, stream>>>(out0, fm);
}

// Round 11
// 72.726 us; speedup vs baseline: 1.0519x; 1.0519x over previous
//
#include <hip/hip_runtime.h>
#include <math.h>

#define D_ 10
#define N_ 500
#define REC 168   // f32 dwords per record; layer blocks even-aligned, 36 dw each

typedef float f32x2 __attribute__((ext_vector_type(2)));

__device__ __forceinline__ float fexp2(float x){ return __builtin_amdgcn_exp2f(x); }
__device__ __forceinline__ float flog2(float x){ return __builtin_amdgcn_logf(x); }
__device__ __forceinline__ float frcp (float x){ return __builtin_amdgcn_rcpf(x); }

#define LOG2E 1.4426950408889634f
#define LN2   0.6931471805599453f

__device__ __forceinline__ float fast_tanh(float x){
  float e = fexp2(x * (2.0f*LOG2E));
  return 1.0f - 2.0f*frcp(e + 1.0f);
}
__device__ __forceinline__ float softplus10(float x){
  float e = fexp2(x * (10.0f*LOG2E));
  return (0.1f*LN2) * flog2(1.0f + e);
}

// packed-f32 tanh + derivative, paired rcp (plain C++, compiler-scheduled)
__device__ __forceinline__ void act_tanh(f32x2 pre, f32x2* th, f32x2* td){
  f32x2 e;
  e.x = fexp2(pre.x * (2.0f*LOG2E));
  e.y = fexp2(pre.y * (2.0f*LOG2E));
  f32x2 p1 = e + 1.0f;
  float pr = p1.x * p1.y;
  float rr = frcp(pr);
  f32x2 rc;
  rc.x = p1.y * rr;
  rc.y = p1.x * rr;
  f32x2 t = 1.0f - 2.0f*rc;
  *th = t;
  *td = 1.0f - t*t;
}

// Record layout (REC=168 dwords):
//   [0..4] W0  [5..9] b0  [10..14] ta0  [15] pad
//   mid l=0..3 at B=16+36l: [B..B+24] W^T (j*5+k), [B+25..29] b, [B+30..34] ta, [B+35] pad
//   [160..164] Wl  [165] b_last  [166..167] pad
__global__ __launch_bounds__(256) void tennet_prep(
    const float* __restrict__ w_first, const float* __restrict__ w_mid,
    const float* __restrict__ w_last, const float* __restrict__ bs,
    const float* __restrict__ b_last, const float* __restrict__ a_all,
    float* __restrict__ rec)
{
  int rid = blockIdx.x*4 + (threadIdx.x >> 6);
  int lane = threadIdx.x & 63;
  int d = rid / N_;
  int n = rid - d*N_;
  float* dst = rec + (unsigned)rid*REC;
  for (int i = lane; i < REC; i += 64) {
    float v = 0.0f;
    if (i < 5)        v = softplus10(w_first[(d*N_+n)*5 + i]);
    else if (i < 10)  v = bs[(d*N_+n)*5 + (i-5)];
    else if (i < 15)  v = fast_tanh(a_all[(d*N_+n)*5 + (i-10)]);
    else if (i == 15) v = 0.0f;
    else if (i < 160) {
      int q = i - 16; int l = q/36; int r2 = q - l*36;
      if (r2 < 25) {
        int j = r2/5, k = r2 - (r2/5)*5;
        v = softplus10(w_mid[((l*D_+d)*N_+n)*25 + k*5 + j]);
      } else if (r2 < 30) {
        v = bs[(((l+1)*D_+d)*N_+n)*5 + (r2-25)];
      } else if (r2 < 35) {
        v = fast_tanh(a_all[(((l+1)*D_+d)*N_+n)*5 + (r2-30)]);
      }
    }
    else if (i < 165)  v = softplus10(w_last[(d*N_+n)*5 + (i-160)]);
    else if (i == 165) v = b_last[d*N_+n];
    dst[i] = v;
  }
}

// One wave per (d,n); 64 lanes x 2 m per thread (m, m+64), packed f32 math.
// Weights staged once per block into LDS (coalesced), read wave-uniform
// (broadcast, conflict-free) -> no s_load bursts on the critical path.
__global__ __launch_bounds__(512) void tennet_main(
    const float* __restrict__ rec, const float* __restrict__ X,
    float* __restrict__ out0)
{
  __shared__ float W[8*REC];    // 5376 B
  __shared__ float tr[128*9];   // 4608 B
  int bid = blockIdx.x;
  int mb  = bid & 7;            // 8 chunks of 128 m
  int q   = bid >> 3;
  int d   = q / 63;             // 10
  int nch = q - d*63;           // 63 chunks of 8 n (covers 504 >= 500)
  int n0 = nch*8;
  int t = threadIdx.x;

  // --- stage 8 records (n0..n0+7, clamped) into LDS, coalesced ---
  for (int i = t; i < 8*REC; i += 512) {
    int s = i / REC;            // record slot
    int off = i - s*REC;
    int nn = n0 + s; if (nn >= N_) nn = N_-1;
    W[i] = rec[(unsigned)(d*N_ + nn)*REC + off];
  }
  __syncthreads();

  int wv = __builtin_amdgcn_readfirstlane(t >> 6);
  int lane = t & 63;
  int n = n0 + wv;
  const float* r = &W[wv*REC];  // wave-uniform LDS pointer -> broadcast reads
  int m0 = mb*128 + lane;

  f32x2 x;
  x.x = X[m0*D_ + d];
  x.y = X[(m0+64)*D_ + d];

  f32x2 phis[5], phid[5];
  // layer 0 (k-dim = 1)
  #pragma unroll
  for (int j = 0; j < 5; ++j) {
    f32x2 pre = x * r[j] + r[5+j];
    f32x2 th, td;
    act_tanh(pre, &th, &td);
    phid[j] = (1.0f + r[10+j]*td) * r[j];
    phis[j] = pre + th * r[10+j];
  }
  // mid layers
  #pragma unroll
  for (int l = 0; l < 4; ++l) {
    const int B = 16 + l*36;
    f32x2 nphis[5], nphid[5];
    #pragma unroll
    for (int j = 0; j < 5; ++j) {
      f32x2 pre = phis[0] * r[B + j*5] + r[B + 25 + j];
      f32x2 pd  = phid[0] * r[B + j*5];
      #pragma unroll
      for (int k = 1; k < 5; ++k) {
        pre += phis[k] * r[B + j*5 + k];
        pd  += phid[k] * r[B + j*5 + k];
      }
      f32x2 th, td;
      act_tanh(pre, &th, &td);
      nphid[j] = pd * (1.0f + r[B + 30 + j]*td);
      nphis[j] = pre + th * r[B + 30 + j];
    }
    #pragma unroll
    for (int j = 0; j < 5; ++j){ phis[j]=nphis[j]; phid[j]=nphid[j]; }
  }
  // last layer + sigmoid' (paired rcp)
  f32x2 pre = phis[0] * r[160] + r[165];
  f32x2 pd  = phid[0] * r[160];
  #pragma unroll
  for (int k = 1; k < 5; ++k) {
    pre += phis[k] * r[160 + k];
    pd  += phid[k] * r[160 + k];
  }
  f32x2 e;
  e.x = fexp2(pre.x * (-LOG2E));
  e.y = fexp2(pre.y * (-LOG2E));
  f32x2 p1 = e + 1.0f;
  float prd = p1.x * p1.y;
  float rrc = frcp(prd);
  f32x2 sg;
  sg.x = p1.y * rrc;
  sg.y = p1.x * rrc;
  f32x2 res = pd * sg * (1.0f - sg);

  // transpose 128m x 8n through LDS (stride 9 -> <=2-way banks, free)
  tr[lane*9 + wv]      = res.x;
  tr[(lane+64)*9 + wv] = res.y;
  __syncthreads();
  int tn = t & 7;
  #pragma unroll
  for (int p = 0; p < 2; ++p) {
    int rr2 = (t >> 3) + p*64;
    if (n0 + tn < N_)
      out0[((mb*128 + rr2)*D_ + d)*N_ + n0 + tn] = tr[rr2*9 + tn];
  }
}

// fm[m] = min_n mean_d( -ln(phidot[m,d,n] + 1e-10) )
__global__ __launch_bounds__(512) void tennet_fm(
    const float* __restrict__ out0, float* __restrict__ fm)
{
  int m = blockIdx.x;
  int t = threadIdx.x;
  float val = INFINITY;
  if (t < N_) {
    float acc = 0.0f;
    #pragma unroll
    for (int d = 0; d < D_; ++d) {
      float v = out0[(m*D_ + d)*N_ + t];
      acc += flog2(v + 1e-10f);
    }
    val = -acc * (LN2 / (float)D_);
  }
  #pragma unroll
  for (int off = 32; off; off >>= 1) {
    float o = __shfl_down(val, off, 64);
    val = fminf(val, o);
  }
  __shared__ float red[8];
  int wid = t >> 6;
  if ((t & 63) == 0) red[wid] = val;
  __syncthreads();
  if (t == 0) {
    float v = red[0];
    #pragma unroll
    for (int ww = 1; ww < 8; ++ww) v = fminf(v, red[ww]);
    fm[m] = v;
  }
}

extern "C" void kernel_launch(void* const* d_in, const int* in_sizes, int n_in,
                              void* d_out, int out_size, void* d_ws, size_t ws_size,
                              hipStream_t stream) {
  const float* X       = (const float*)d_in[0];
  const float* w_first = (const float*)d_in[1];
  const float* w_mid   = (const float*)d_in[2];
  const float* w_last  = (const float*)d_in[3];
  const float* bs      = (const float*)d_in[4];
  const float* b_last  = (const float*)d_in[5];
  const float* a_all   = (const float*)d_in[6];
  float* out0 = (float*)d_out;
  float* fm   = out0 + 1024*D_*N_;
  float* rec  = (float*)d_ws;   // 10*500*168*4 = 3.36 MB

  tennet_prep<<<(D_*N_)/4, 256, 0, stream>>>(w_first, w_mid, w_last, bs, b_last, a_all, rec);
  tennet_main<<<10*63*8, 512, 0, stream>>>(rec, X, out0);
  tennet_fm<<<1024, 512, 0, stream>>>(out0, fm);
}

// Round 12
// 66.555 us; speedup vs baseline: 1.1494x; 1.0927x over previous
//
#include <hip/hip_runtime.h>
#include <math.h>

#define D_ 10
#define N_ 500
#define REC 164   // packed per-(d,n) weight record, floats

typedef float f32x2 __attribute__((ext_vector_type(2)));

__device__ __forceinline__ float fexp2(float x){ return __builtin_amdgcn_exp2f(x); }
__device__ __forceinline__ float flog2(float x){ return __builtin_amdgcn_logf(x); }
__device__ __forceinline__ float frcp (float x){ return __builtin_amdgcn_rcpf(x); }

#define LOG2E 1.4426950408889634f
#define LN2   0.6931471805599453f

__device__ __forceinline__ float fast_tanh(float x){
  float e = fexp2(x * (2.0f*LOG2E));
  return 1.0f - 2.0f*frcp(e + 1.0f);
}
__device__ __forceinline__ float softplus10(float x){
  float e = fexp2(x * (10.0f*LOG2E));
  return (0.1f*LN2) * flog2(1.0f + e);
}

// packed-f32 tanh + derivative, paired rcp (plain C++, compiler-scheduled)
__device__ __forceinline__ void act_tanh(f32x2 pre, f32x2* th, f32x2* td){
  f32x2 e;
  e.x = fexp2(pre.x * (2.0f*LOG2E));
  e.y = fexp2(pre.y * (2.0f*LOG2E));
  f32x2 p1 = e + 1.0f;
  float pr = p1.x * p1.y;
  float rr = frcp(pr);
  f32x2 rc;
  rc.x = p1.y * rr;
  rc.y = p1.x * rr;
  f32x2 t = 1.0f - 2.0f*rc;
  *th = t;
  *td = 1.0f - t*t;
}

// Record layout (161 used, padded to 164):
//   [0..4] W0   [5..9] bs0   [10..14] ta0
//   mid l=0..3 at base 15+l*35: [base+j*5+k]=W^T, [base+25+j]=bs, [base+30+j]=ta
//   [155..159] Wl   [160] b_last
__global__ __launch_bounds__(256) void tennet_prep(
    const float* __restrict__ w_first, const float* __restrict__ w_mid,
    const float* __restrict__ w_last, const float* __restrict__ bs,
    const float* __restrict__ b_last, const float* __restrict__ a_all,
    float* __restrict__ rec)
{
  int rid = blockIdx.x*4 + (threadIdx.x >> 6);
  int lane = threadIdx.x & 63;
  int d = rid / N_;
  int n = rid - d*N_;
  float* dst = rec + (unsigned)rid*REC;
  for (int i = lane; i < 161; i += 64) {
    float v;
    if (i < 5)        v = softplus10(w_first[(d*N_+n)*5 + i]);
    else if (i < 10)  v = bs[(d*N_+n)*5 + (i-5)];
    else if (i < 15)  v = fast_tanh(a_all[(d*N_+n)*5 + (i-10)]);
    else if (i < 155) {
      int q = i - 15; int l = q/35; int r2 = q - l*35;
      if (r2 < 25) {
        int j = r2/5, k = r2 - (r2/5)*5;
        v = softplus10(w_mid[((l*D_+d)*N_+n)*25 + k*5 + j]);
      } else if (r2 < 30) {
        v = bs[(((l+1)*D_+d)*N_+n)*5 + (r2-25)];
      } else {
        v = fast_tanh(a_all[(((l+1)*D_+d)*N_+n)*5 + (r2-30)]);
      }
    }
    else if (i < 160) v = softplus10(w_last[(d*N_+n)*5 + (i-155)]);
    else              v = b_last[d*N_+n];
    dst[i] = v;
  }
}

// One wave per (d,n); 64 lanes x 4 m per thread (two f32x2 streams A={m,m+64},
// B={m+128,m+192}) sharing one record's s_loads -> scalar-load stall per unit
// work halves. 512-thread blocks keep VGPR~44 and 8-wave/SIMD capacity (the
// fix for R5's occupancy crash at 1024 threads).
__global__ __launch_bounds__(512) void tennet_main(
    const float* __restrict__ X, const float* __restrict__ rec,
    float* __restrict__ out0)
{
  __shared__ float tr[256*9];
  int bid = blockIdx.x;
  int mb  = bid & 3;            // 4 chunks of 256 m
  int q   = bid >> 2;
  int d   = q / 63;             // 10
  int nch = q - d*63;           // 63 chunks of 8 n (covers 504 >= 500)
  int n0 = nch*8;
  int t = threadIdx.x;
  int wv = __builtin_amdgcn_readfirstlane(t >> 6);   // uniform -> s_load weights
  int lane = t & 63;
  int n = n0 + wv;
  int nr = (n < N_) ? n : (N_-1);
  const float* r = rec + (unsigned)(d*N_ + nr)*REC;  // wave-uniform -> s_load
  int m0 = mb*256 + lane;

  f32x2 xA, xB;
  xA.x = X[m0*D_ + d];
  xA.y = X[(m0+64)*D_ + d];
  xB.x = X[(m0+128)*D_ + d];
  xB.y = X[(m0+192)*D_ + d];

  f32x2 phisA[5], phidA[5], phisB[5], phidB[5];
  // layer 0 (k-dim = 1)
  #pragma unroll
  for (int j = 0; j < 5; ++j) {
    f32x2 preA = xA * r[j] + r[5+j];
    f32x2 preB = xB * r[j] + r[5+j];
    f32x2 thA, tdA, thB, tdB;
    act_tanh(preA, &thA, &tdA);
    act_tanh(preB, &thB, &tdB);
    phidA[j] = (1.0f + r[10+j]*tdA) * r[j];
    phidB[j] = (1.0f + r[10+j]*tdB) * r[j];
    phisA[j] = preA + thA * r[10+j];
    phisB[j] = preB + thB * r[10+j];
  }
  // mid layers
  #pragma unroll
  for (int l = 0; l < 4; ++l) {
    const int B = 15 + l*35;
    f32x2 nsA[5], ndA[5], nsB[5], ndB[5];
    #pragma unroll
    for (int j = 0; j < 5; ++j) {
      f32x2 preA = phisA[0] * r[B + j*5] + r[B + 25 + j];
      f32x2 preB = phisB[0] * r[B + j*5] + r[B + 25 + j];
      f32x2 pdA  = phidA[0] * r[B + j*5];
      f32x2 pdB  = phidB[0] * r[B + j*5];
      #pragma unroll
      for (int k = 1; k < 5; ++k) {
        preA += phisA[k] * r[B + j*5 + k];
        preB += phisB[k] * r[B + j*5 + k];
        pdA  += phidA[k] * r[B + j*5 + k];
        pdB  += phidB[k] * r[B + j*5 + k];
      }
      f32x2 thA, tdA, thB, tdB;
      act_tanh(preA, &thA, &tdA);
      act_tanh(preB, &thB, &tdB);
      ndA[j] = pdA * (1.0f + r[B + 30 + j]*tdA);
      ndB[j] = pdB * (1.0f + r[B + 30 + j]*tdB);
      nsA[j] = preA + thA * r[B + 30 + j];
      nsB[j] = preB + thB * r[B + 30 + j];
    }
    #pragma unroll
    for (int j = 0; j < 5; ++j){
      phisA[j]=nsA[j]; phidA[j]=ndA[j];
      phisB[j]=nsB[j]; phidB[j]=ndB[j];
    }
  }
  // last layer + sigmoid' (paired rcp per stream)
  f32x2 preA = phisA[0] * r[155] + r[160];
  f32x2 preB = phisB[0] * r[155] + r[160];
  f32x2 pdA  = phidA[0] * r[155];
  f32x2 pdB  = phidB[0] * r[155];
  #pragma unroll
  for (int k = 1; k < 5; ++k) {
    preA += phisA[k] * r[155 + k];
    preB += phisB[k] * r[155 + k];
    pdA  += phidA[k] * r[155 + k];
    pdB  += phidB[k] * r[155 + k];
  }
  f32x2 eA, eB;
  eA.x = fexp2(preA.x * (-LOG2E));
  eA.y = fexp2(preA.y * (-LOG2E));
  eB.x = fexp2(preB.x * (-LOG2E));
  eB.y = fexp2(preB.y * (-LOG2E));
  f32x2 p1A = eA + 1.0f, p1B = eB + 1.0f;
  float rrA = frcp(p1A.x * p1A.y);
  float rrB = frcp(p1B.x * p1B.y);
  f32x2 sgA, sgB;
  sgA.x = p1A.y * rrA; sgA.y = p1A.x * rrA;
  sgB.x = p1B.y * rrB; sgB.y = p1B.x * rrB;
  f32x2 resA = pdA * sgA * (1.0f - sgA);
  f32x2 resB = pdB * sgB * (1.0f - sgB);

  // transpose 256m x 8n through LDS (stride 9 -> <=2-way banks, free)
  tr[lane*9 + wv]       = resA.x;
  tr[(lane+64)*9 + wv]  = resA.y;
  tr[(lane+128)*9 + wv] = resB.x;
  tr[(lane+192)*9 + wv] = resB.y;
  __syncthreads();
  int tn = t & 7;
  #pragma unroll
  for (int p = 0; p < 4; ++p) {
    int rr2 = (t >> 3) + p*64;
    if (n0 + tn < N_)
      out0[((mb*256 + rr2)*D_ + d)*N_ + n0 + tn] = tr[rr2*9 + tn];
  }
}

// fm[m] = min_n mean_d( -ln(phidot[m,d,n] + 1e-10) )
__global__ __launch_bounds__(512) void tennet_fm(
    const float* __restrict__ out0, float* __restrict__ fm)
{
  int m = blockIdx.x;
  int t = threadIdx.x;
  float val = INFINITY;
  if (t < N_) {
    float acc = 0.0f;
    #pragma unroll
    for (int d = 0; d < D_; ++d) {
      float v = out0[(m*D_ + d)*N_ + t];
      acc += flog2(v + 1e-10f);
    }
    val = -acc * (LN2 / (float)D_);
  }
  #pragma unroll
  for (int off = 32; off; off >>= 1) {
    float o = __shfl_down(val, off, 64);
    val = fminf(val, o);
  }
  __shared__ float red[8];
  int wid = t >> 6;
  if ((t & 63) == 0) red[wid] = val;
  __syncthreads();
  if (t == 0) {
    float v = red[0];
    #pragma unroll
    for (int ww = 1; ww < 8; ++ww) v = fminf(v, red[ww]);
    fm[m] = v;
  }
}

extern "C" void kernel_launch(void* const* d_in, const int* in_sizes, int n_in,
                              void* d_out, int out_size, void* d_ws, size_t ws_size,
                              hipStream_t stream) {
  const float* X       = (const float*)d_in[0];
  const float* w_first = (const float*)d_in[1];
  const float* w_mid   = (const float*)d_in[2];
  const float* w_last  = (const float*)d_in[3];
  const float* bs      = (const float*)d_in[4];
  const float* b_last  = (const float*)d_in[5];
  const float* a_all   = (const float*)d_in[6];
  float* out0 = (float*)d_out;
  float* fm   = out0 + 1024*D_*N_;
  float* rec  = (float*)d_ws;   // 10*500*164*4 = 3.28 MB

  tennet_prep<<<(D_*N_)/4, 256, 0, stream>>>(w_first, w_mid, w_last, bs, b_last, a_all, rec);
  tennet_main<<<10*63*4, 512, 0, stream>>>(X, rec, out0);
  tennet_fm<<<1024, 512, 0, stream>>>(out0, fm);
}